// Round 16
// baseline (114.972 us; speedup 1.0000x reference)
//
#include <hip/hip_runtime.h>
#include <math.h>

#define HW 1024
#define Hd 32
#define Wd 32
#define Bn 8
#define Cc 256

typedef _Float16 half2_t __attribute__((ext_vector_type(2)));
union F2H { float f; half2_t h; };

static __device__ __forceinline__ float dot2(half2_t a, half2_t b, float c) {
#if __has_builtin(__builtin_amdgcn_fdot2)
    return __builtin_amdgcn_fdot2(a, b, c, false);
#else
    return c + (float)a.x * (float)b.x + (float)a.y * (float)b.y;
#endif
}

// DPP lane-xor on the VALU pipe (no DS). CTRL: 0xB1=xor1, 0x4E=xor2,
// 0x128=row_ror:8=xor8 (within 16-lane rows).
template<int CTRL>
static __device__ __forceinline__ float dppx(float v) {
    union { float f; int i; } a, r;
    a.f = v;
    r.i = __builtin_amdgcn_update_dpp(0, a.i, CTRL, 0xF, 0xF, true);
    return r.f;
}

// ---------------- Kernel TP: x-transpose + weight prep (merged) -------------
// bid<512: transpose x[b][c][hw] -> xt[pix][c]
// 512..583: conv-w transpose to wt2[tap][oc][c]
// 584..711: routing-W fp16 pack wth[j=o*16+d][l][i]
// lane map (kD): half = l bit2; n = {l0,l1,l3,l4,l5}
__global__ __launch_bounds__(256) void kTP(const float* __restrict__ x,
        const float* __restrict__ ow, const float* __restrict__ rw,
        float* __restrict__ xt, float* __restrict__ wt2,
        _Float16* __restrict__ wth) {
    __shared__ float tile[64][65];
    int bid = blockIdx.x;
    if (bid < 512) {
        int b = bid >> 6, ct = (bid >> 4) & 3, ht = bid & 15;
        int c0 = ct * 64, hw0 = ht * 64;
        int tr = threadIdx.x >> 6, tc = threadIdx.x & 63;
        const float* xb = x + ((size_t)b * 256 + c0) * 1024 + hw0;
        #pragma unroll
        for (int k = 0; k < 16; ++k) {
            int c = tr + k * 4;
            tile[c][tc] = xb[(size_t)c * 1024 + tc];
        }
        __syncthreads();
        float* xo = xt + ((size_t)b * 1024 + hw0) * 256 + c0;
        #pragma unroll
        for (int k = 0; k < 16; ++k) {
            int hwl = tr + k * 4;
            xo[(size_t)hwl * 256 + tc] = tile[tc][hwl];
        }
    } else if (bid < 584) {
        int t = (bid - 512) * 256 + threadIdx.x;  // 18432
        int c = t & 255, oc = (t >> 8) & 7, tap = t >> 11;
        wt2[t] = ow[(oc * 256 + c) * 9 + tap];
    } else {
        int t = (bid - 584) * 256 + threadIdx.x;  // 32768
        int i = t & 7, l = (t >> 3) & 63, j = t >> 9;
        int n = (l & 3) | ((l >> 1) & 0x1C);      // kD lane map
        int half = (l >> 2) & 1;
        int o = j >> 4, d = j & 15;
        wth[t] = (_Float16)rw[n * 1024 + half * 512 + o * 128 + d * 8 + i];
    }
}

// ---------------- Kernel AB: primary caps  +  offset conv (block-split) -----
__global__ __launch_bounds__(256) void kAB(const float* __restrict__ xt,
        const float* __restrict__ pw, const float* __restrict__ gamma,
        const float* __restrict__ beta, const float* __restrict__ mean,
        const float* __restrict__ var, const float* __restrict__ wt2,
        const float* __restrict__ ob, float* __restrict__ child_t,
        float* __restrict__ grids) {
    __shared__ float wl[16384];               // 64 KB, both roles
    int wid = threadIdx.x >> 6, lane = threadIdx.x & 63;

    if (blockIdx.x < 512) {
        // ================= kA role =================
        {
            const float4* pw4 = reinterpret_cast<const float4*>(pw);
            #pragma unroll
            for (int k = 0; k < 16; ++k) {
                int f = k * 256 + threadIdx.x;
                float4 v = pw4[f];
                int o = f >> 6, c4 = f & 63;
                *reinterpret_cast<float4*>(
                    wl + c4 * 256 + (((o ^ c4) & 63) << 2)) = v;
            }
        }
        __syncthreads();
        int o = lane;
        float scale = gamma[o] * rsqrtf(var[o] + 1e-5f);
        float mn = mean[o], bt = beta[o];
        const float4* wl4 = reinterpret_cast<const float4*>(wl);
        #pragma unroll
        for (int pp = 0; pp < 4; pp += 2) {   // 2 pixels share each weight pass
            int m0 = (blockIdx.x * 4 + wid) * 4 + pp;
            const float4* xa = reinterpret_cast<const float4*>(xt + (size_t)m0 * 256);
            const float4* xb = reinterpret_cast<const float4*>(xt + (size_t)(m0 + 1) * 256);
            float a0 = 0.f, a1 = 0.f;
            #pragma unroll 8
            for (int c4 = 0; c4 < 64; ++c4) {
                float4 wv = wl4[c4 * 64 + (lane ^ (c4 & 63))];
                float4 v0 = xa[c4], v1 = xb[c4];
                a0 += wv.x * v0.x + wv.y * v0.y + wv.z * v0.z + wv.w * v0.w;
                a1 += wv.x * v1.x + wv.y * v1.y + wv.z * v1.z + wv.w * v1.w;
            }
            #pragma unroll
            for (int e = 0; e < 2; ++e) {
                float acc = e ? a1 : a0;
                float t = (acc - mn) * scale + bt;
                float s = t / (1.f + expf(-t));      // SiLU
                float sq = s * s;                     // squash over 8-lane group
                sq += __shfl_xor(sq, 1);
                sq += __shfl_xor(sq, 2);
                sq += __shfl_xor(sq, 4);
                float f = (sq / (1.f + sq)) * rsqrtf(sq + 1e-7f);
                child_t[(size_t)(m0 + e) * 64 + o] = s * f;
            }
        }
        return;
    }

    // ================= kB role =================
    {
        const float4* wt24 = reinterpret_cast<const float4*>(wt2);
        float4* wl4w = reinterpret_cast<float4*>(wl);
        #pragma unroll
        for (int k = 0; k < 16; ++k)
            wl4w[k * 256 + threadIdx.x] = wt24[k * 256 + threadIdx.x];
    }
    __syncthreads();

    int m0 = ((blockIdx.x - 512) * 4 + wid) * 4;  // 4 consecutive px, same row
    int b = m0 >> 10, hw0 = m0 & 1023;
    int yy = hw0 >> 5, xx0 = hw0 & 31;
    const float* xb = xt + (size_t)b * HW * 256;

    float acc[4][8];
    #pragma unroll
    for (int px = 0; px < 4; ++px)
        #pragma unroll
        for (int oc = 0; oc < 8; ++oc) acc[px][oc] = 0.f;

    #pragma unroll
    for (int tap = 0; tap < 9; ++tap) {
        int ky = tap / 3 - 1, kx = tap % 3 - 1;
        int yq = yy + ky;
        bool vy = (yq >= 0) && (yq <= Hd - 1);
        float4 xv[4];
        #pragma unroll
        for (int px = 0; px < 4; ++px) {
            int xq = xx0 + px + kx;
            bool ok = vy && (xq >= 0) && (xq <= Wd - 1);
            float4 z; z.x = z.y = z.z = z.w = 0.f;
            xv[px] = ok ? *reinterpret_cast<const float4*>(
                              xb + (size_t)(yq * Wd + xq) * 256 + lane * 4)
                        : z;
        }
        #pragma unroll
        for (int oc = 0; oc < 8; ++oc) {
            float4 wv = (tap < 8)
                ? *reinterpret_cast<const float4*>(wl + (tap * 8 + oc) * 256 + lane * 4)
                : *reinterpret_cast<const float4*>(wt2 + (8 * 8 + oc) * 256 + lane * 4);
            #pragma unroll
            for (int px = 0; px < 4; ++px)
                acc[px][oc] += xv[px].x * wv.x + xv[px].y * wv.y +
                               xv[px].z * wv.z + xv[px].w * wv.w;
        }
    }

    // reduce-scatter to lane target (px = lane&3, oc = (lane>>2)&7)
    int l0 = lane & 1, l1 = (lane >> 1) & 1;
    int o2 = (lane >> 2) & 1, o3 = (lane >> 3) & 1, o4 = (lane >> 4) & 1;
    float y1[2][8];
    #pragma unroll
    for (int ph = 0; ph < 2; ++ph)
        #pragma unroll
        for (int oc = 0; oc < 8; ++oc) {
            float keep = l0 ? acc[(ph << 1) | 1][oc] : acc[(ph << 1) | 0][oc];
            float send = l0 ? acc[(ph << 1) | 0][oc] : acc[(ph << 1) | 1][oc];
            y1[ph][oc] = keep + dppx<0xB1>(send);
        }
    float y2[8];
    #pragma unroll
    for (int oc = 0; oc < 8; ++oc) {
        float keep = l1 ? y1[1][oc] : y1[0][oc];
        float send = l1 ? y1[0][oc] : y1[1][oc];
        y2[oc] = keep + dppx<0x4E>(send);
    }
    float z4[4];
    #pragma unroll
    for (int oh = 0; oh < 4; ++oh) {
        float keep = o2 ? y2[(oh << 1) | 1] : y2[(oh << 1) | 0];
        float send = o2 ? y2[(oh << 1) | 0] : y2[(oh << 1) | 1];
        z4[oh] = keep + __shfl_xor(send, 4);
    }
    float w2[2];
    #pragma unroll
    for (int oh = 0; oh < 2; ++oh) {
        float keep = o3 ? z4[(oh << 1) | 1] : z4[(oh << 1) | 0];
        float send = o3 ? z4[(oh << 1) | 0] : z4[(oh << 1) | 1];
        w2[oh] = keep + dppx<0x128>(send);
    }
    {
        float keep = o4 ? w2[1] : w2[0];
        float send = o4 ? w2[0] : w2[1];
        float s = keep + __shfl_xor(send, 16);
        s += __shfl_xor(s, 32);
        if (lane < 32) {
            int px = lane & 3, oc = (lane >> 2) & 7;
            float t = tanhf(s + ob[oc]);
            int coord = oc & 1, si = oc >> 1;
            int xx = xx0 + px;
            float base = coord ? (-1.f + yy * (2.f / 31.f))
                               : (-1.f + xx * (2.f / 31.f));
            grids[(size_t)(m0 + px) * 8 + si * 2 + coord] =
                base + t * (1.f / 15.5f);
        }
    }
}

// ---------------- Kernel D v13: v7 body, NO launch_bounds -------------------
// 2048 blocks x 256 thr (4 waves), 1 pixel/wave. fp16 weights from L2.
// No __launch_bounds__: tests whether hipcc's waves-per-eu max (from the 2nd
// arg) was capping residency at 2/SIMD despite 84 VGPR (HW tier allows 4).
__global__ void kD(const float* __restrict__ child_t,
        const float* __restrict__ grids, const _Float16* __restrict__ wth,
        float* __restrict__ out) {
    __shared__ float vband_s[4][128];         // per-wave v broadcast, 2 KB
    int wid = threadIdx.x >> 6, lane = threadIdx.x & 63;
    float* vband = vband_s[wid];
    int m = blockIdx.x * 4 + wid;             // pixel
    int b = m >> 10, hw = m & 1023;
    int n = (lane & 3) | ((lane >> 1) & 0x1C);
    int half = (lane >> 2) & 1;
    int si = n >> 3, ch = n & 7;
    // d-slot owned after reduce-scatter (bit-reversed n bits 0..3)
    int dsl = (n & 1) * 8 + ((n >> 1) & 1) * 4 + ((n >> 2) & 1) * 2 + ((n >> 3) & 1);

    // ---- bilinear sampling (align_corners=True, zeros padding), f32 ----
    float gx = grids[m * 8 + si * 2 + 0];
    float gy = grids[m * 8 + si * 2 + 1];
    float xf = (gx + 1.f) * 0.5f * 31.f;
    float yf = (gy + 1.f) * 0.5f * 31.f;
    float x0 = floorf(xf), y0 = floorf(yf);
    float wx1 = xf - x0, wx0 = 1.f - wx1;
    float wy1 = yf - y0, wy0 = 1.f - wy1;
    float sf[8] = {0.f, 0.f, 0.f, 0.f, 0.f, 0.f, 0.f, 0.f};
    const float* cb = child_t + (size_t)b * HW * 64 + ch * 8;
    #pragma unroll
    for (int cy = 0; cy < 2; ++cy) {
        float yq = y0 + (float)cy;
        bool vy = (yq >= 0.f) && (yq <= 31.f);
        float wy = cy ? wy1 : wy0;
        #pragma unroll
        for (int cx = 0; cx < 2; ++cx) {
            float xq = x0 + (float)cx;
            bool ok = vy && (xq >= 0.f) && (xq <= 31.f);
            if (!ok) continue;
            float w = wy * (cx ? wx1 : wx0);
            const float* cp = cb + (size_t)((int)yq * Wd + (int)xq) * 64;
            float4 v0 = *reinterpret_cast<const float4*>(cp);
            float4 v1 = *reinterpret_cast<const float4*>(cp + 4);
            sf[0] += w * v0.x; sf[1] += w * v0.y;
            sf[2] += w * v0.z; sf[3] += w * v0.w;
            sf[4] += w * v1.x; sf[5] += w * v1.y;
            sf[6] += w * v1.z; sf[7] += w * v1.w;
        }
    }
    half2_t sh0 = {(_Float16)sf[0], (_Float16)sf[1]};
    half2_t sh1 = {(_Float16)sf[2], (_Float16)sf[3]};
    half2_t sh2 = {(_Float16)sf[4], (_Float16)sf[5]};
    half2_t sh3 = {(_Float16)sf[6], (_Float16)sf[7]};

    // ---- u_hat = W[n] . samp : fp16 from global/L2, coalesced b128 ----
    float u[4][16];
    const float4* wt4 = reinterpret_cast<const float4*>(wth);
    #pragma unroll
    for (int o = 0; o < 4; ++o) {
        #pragma unroll
        for (int d = 0; d < 16; ++d) {
            float4 wv = wt4[(o * 16 + d) * 64 + lane];
            F2H a0, a1, a2, a3;
            a0.f = wv.x; a1.f = wv.y; a2.f = wv.z; a3.f = wv.w;
            float acc = dot2(a0.h, sh0, 0.f);
            acc = dot2(a1.h, sh1, acc);
            acc = dot2(a2.h, sh2, acc);
            acc = dot2(a3.h, sh3, acc);
            u[o][d] = acc;
        }
    }

    // ---- dynamic routing (3 iters); iter 0 has exact c = 1/8 ----
    float bl[4] = {0.f, 0.f, 0.f, 0.f};
    #pragma unroll
    for (int it = 0; it < 3; ++it) {
        float ex[4], rs;
        if (it == 0) {
            ex[0] = ex[1] = ex[2] = ex[3] = 1.f;
            rs = 0.125f;                      // softmax(0) = 1/8 exactly
        } else {
            float mx = fmaxf(fmaxf(bl[0], bl[1]), fmaxf(bl[2], bl[3]));
            mx = fmaxf(mx, __shfl_xor(mx, 4));     // half partner = xor4
            float ssum = 0.f;
            #pragma unroll
            for (int k = 0; k < 4; ++k) { ex[k] = expf(bl[k] - mx); ssum += ex[k]; }
            ssum += __shfl_xor(ssum, 4);
            rs = 1.f / ssum;
        }

        float sval[4];
        #pragma unroll
        for (int o = 0; o < 4; ++o) {
            float cc = ex[o] * rs;
            // reduce-scatter over n: xor1(DPP), xor2(DPP), xor8(DPP),
            // xor16(DS), xor32(DS)
            float y[8];
            #pragma unroll
            for (int d = 0; d < 8; ++d) {
                float t = (n & 1) ? cc * u[o][d] : cc * u[o][d + 8]; // send
                float k = (n & 1) ? cc * u[o][d + 8] : cc * u[o][d]; // keep
                y[d] = k + dppx<0xB1>(t);
            }
            float z[4];
            #pragma unroll
            for (int d = 0; d < 4; ++d) {
                float t = (n & 2) ? y[d] : y[d + 4];
                float k = (n & 2) ? y[d + 4] : y[d];
                z[d] = k + dppx<0x4E>(t);
            }
            float w2[2];
            #pragma unroll
            for (int d = 0; d < 2; ++d) {
                float t = (n & 4) ? z[d] : z[d + 2];
                float k = (n & 4) ? z[d + 2] : z[d];
                w2[d] = k + dppx<0x128>(t);
            }
            float t4 = (n & 8) ? w2[0] : w2[1];
            float k4 = (n & 8) ? w2[1] : w2[0];
            float s1 = k4 + __shfl_xor(t4, 16);
            s1 += __shfl_xor(s1, 32);                 // merge n-bit4 halves
            sval[o] = s1;
        }
        // squash: sq_o = sum over 16 d-owners (lane bits {0,1,3,4})
        #pragma unroll
        for (int o = 0; o < 4; ++o) {
            float q = sval[o] * sval[o];
            q += dppx<0xB1>(q);
            q += dppx<0x4E>(q);
            q += dppx<0x128>(q);
            q += __shfl_xor(q, 16);
            float f = (q / (1.f + q)) / sqrtf(q + 1e-7f);
            if ((lane & 32) == 0)                     // one writer per (o,d)
                vband[(half * 4 + o) * 16 + dsl] = sval[o] * f;
        }
        if (it < 2) {
            // agreement: b[n][o] += sum_d u[n][o][d] * v[o][d]
            #pragma unroll
            for (int o = 0; o < 4; ++o) {
                const float4* vr = reinterpret_cast<const float4*>(
                    vband + (half * 4 + o) * 16);
                float4 v0 = vr[0], v1 = vr[1], v2 = vr[2], v3 = vr[3];
                float agg = u[o][0] * v0.x + u[o][1] * v0.y +
                            u[o][2] * v0.z + u[o][3] * v0.w +
                            u[o][4] * v1.x + u[o][5] * v1.y +
                            u[o][6] * v1.z + u[o][7] * v1.w +
                            u[o][8] * v2.x + u[o][9] * v2.y +
                            u[o][10] * v2.z + u[o][11] * v2.w +
                            u[o][12] * v3.x + u[o][13] * v3.y +
                            u[o][14] * v3.z + u[o][15] * v3.w;
                bl[o] += agg;
            }
        } else {
            // output: each lane writes 2 dwords of out[b][och][d][hw]
            int o_own = lane >> 4;                    // bits 4,5
            int och = half * 4 + o_own;
            int d0 = ((lane & 3) | ((lane >> 1) & 4)) * 2;  // bits {0,1,3}
            float va = vband[och * 16 + d0 + 0];
            float vb = vband[och * 16 + d0 + 1];
            float* op = out + ((size_t)b * 128 + och * 16) * HW + hw;
            op[(size_t)(d0 + 0) * HW] = va;
            op[(size_t)(d0 + 1) * HW] = vb;
        }
    }
}

extern "C" void kernel_launch(void* const* d_in, const int* in_sizes, int n_in,
                              void* d_out, int out_size, void* d_ws, size_t ws_size,
                              hipStream_t stream) {
    const float* x     = (const float*)d_in[0];
    const float* pw    = (const float*)d_in[1];
    const float* gamma = (const float*)d_in[2];
    const float* beta  = (const float*)d_in[3];
    const float* mean  = (const float*)d_in[4];
    const float* var   = (const float*)d_in[5];
    const float* ow    = (const float*)d_in[6];
    const float* ob    = (const float*)d_in[7];
    const float* rw    = (const float*)d_in[8];
    float* out = (float*)d_out;
    char* ws = (char*)d_ws;
    float*     child_t = (float*)ws;                 // 2 MiB
    float*     grids   = (float*)(ws + 2097152);     // 256 KiB
    _Float16*  wth     = (_Float16*)(ws + 2359296);  // 64 KiB
    float*     wt2     = (float*)(ws + 2424832);     // 72 KiB
    float*     xt      = (float*)(ws + 2498560);     // 8 MiB

    hipLaunchKernelGGL(kTP, dim3(712), dim3(256), 0, stream,
                       x, ow, rw, xt, wt2, wth);
    hipLaunchKernelGGL(kAB, dim3(1024), dim3(256), 0, stream,
                       xt, pw, gamma, beta, mean, var, wt2, ob,
                       child_t, grids);
    hipLaunchKernelGGL(kD, dim3(2048), dim3(256), 0, stream,
                       child_t, grids, wth, out);
}

// Round 17
// 91.136 us; speedup vs baseline: 1.2615x; 1.2615x over previous
//
#include <hip/hip_runtime.h>
#include <math.h>

#define HW 1024
#define Hd 32
#define Wd 32
#define Bn 8
#define Cc 256

typedef _Float16 half2_t __attribute__((ext_vector_type(2)));
union F2H { float f; half2_t h; };

static __device__ __forceinline__ float dot2(half2_t a, half2_t b, float c) {
#if __has_builtin(__builtin_amdgcn_fdot2)
    return __builtin_amdgcn_fdot2(a, b, c, false);
#else
    return c + (float)a.x * (float)b.x + (float)a.y * (float)b.y;
#endif
}

// DPP lane-xor on the VALU pipe (no DS). CTRL: 0xB1=xor1, 0x4E=xor2,
// 0x128=row_ror:8=xor8 (within 16-lane rows).
template<int CTRL>
static __device__ __forceinline__ float dppx(float v) {
    union { float f; int i; } a, r;
    a.f = v;
    r.i = __builtin_amdgcn_update_dpp(0, a.i, CTRL, 0xF, 0xF, true);
    return r.f;
}

// ---------------- Kernel TP: x-transpose + weight prep (merged) -------------
// bid<512: transpose x[b][c][hw] -> xt[pix][c]
// 512..583: conv-w transpose to wt2[tap][oc][c]
// 584..711: routing-W fp16 pack wth[j=o*16+d][l][i]
// lane map (kD): half = l bit2; n = {l0,l1,l3,l4,l5}
__global__ __launch_bounds__(256) void kTP(const float* __restrict__ x,
        const float* __restrict__ ow, const float* __restrict__ rw,
        float* __restrict__ xt, float* __restrict__ wt2,
        _Float16* __restrict__ wth) {
    __shared__ float tile[64][65];
    int bid = blockIdx.x;
    if (bid < 512) {
        int b = bid >> 6, ct = (bid >> 4) & 3, ht = bid & 15;
        int c0 = ct * 64, hw0 = ht * 64;
        int tr = threadIdx.x >> 6, tc = threadIdx.x & 63;
        const float* xb = x + ((size_t)b * 256 + c0) * 1024 + hw0;
        #pragma unroll
        for (int k = 0; k < 16; ++k) {
            int c = tr + k * 4;
            tile[c][tc] = xb[(size_t)c * 1024 + tc];
        }
        __syncthreads();
        float* xo = xt + ((size_t)b * 1024 + hw0) * 256 + c0;
        #pragma unroll
        for (int k = 0; k < 16; ++k) {
            int hwl = tr + k * 4;
            xo[(size_t)hwl * 256 + tc] = tile[tc][hwl];
        }
    } else if (bid < 584) {
        int t = (bid - 512) * 256 + threadIdx.x;  // 18432
        int c = t & 255, oc = (t >> 8) & 7, tap = t >> 11;
        wt2[t] = ow[(oc * 256 + c) * 9 + tap];
    } else {
        int t = (bid - 584) * 256 + threadIdx.x;  // 32768
        int i = t & 7, l = (t >> 3) & 63, j = t >> 9;
        int n = (l & 3) | ((l >> 1) & 0x1C);      // kD lane map
        int half = (l >> 2) & 1;
        int o = j >> 4, d = j & 15;
        wth[t] = (_Float16)rw[n * 1024 + half * 512 + o * 128 + d * 8 + i];
    }
}

// ---------------- Kernel AB: primary caps  +  offset conv (block-split) -----
__global__ __launch_bounds__(256) void kAB(const float* __restrict__ xt,
        const float* __restrict__ pw, const float* __restrict__ gamma,
        const float* __restrict__ beta, const float* __restrict__ mean,
        const float* __restrict__ var, const float* __restrict__ wt2,
        const float* __restrict__ ob, float* __restrict__ child_t,
        float* __restrict__ grids) {
    __shared__ float wl[16384];               // 64 KB, both roles
    int wid = threadIdx.x >> 6, lane = threadIdx.x & 63;

    if (blockIdx.x < 512) {
        // ================= kA role =================
        {
            const float4* pw4 = reinterpret_cast<const float4*>(pw);
            #pragma unroll
            for (int k = 0; k < 16; ++k) {
                int f = k * 256 + threadIdx.x;
                float4 v = pw4[f];
                int o = f >> 6, c4 = f & 63;
                *reinterpret_cast<float4*>(
                    wl + c4 * 256 + (((o ^ c4) & 63) << 2)) = v;
            }
        }
        __syncthreads();
        int o = lane;
        float scale = gamma[o] * rsqrtf(var[o] + 1e-5f);
        float mn = mean[o], bt = beta[o];
        const float4* wl4 = reinterpret_cast<const float4*>(wl);
        #pragma unroll
        for (int pp = 0; pp < 4; pp += 2) {   // 2 pixels share each weight pass
            int m0 = (blockIdx.x * 4 + wid) * 4 + pp;
            const float4* xa = reinterpret_cast<const float4*>(xt + (size_t)m0 * 256);
            const float4* xb = reinterpret_cast<const float4*>(xt + (size_t)(m0 + 1) * 256);
            float a0 = 0.f, a1 = 0.f;
            #pragma unroll 8
            for (int c4 = 0; c4 < 64; ++c4) {
                float4 wv = wl4[c4 * 64 + (lane ^ (c4 & 63))];
                float4 v0 = xa[c4], v1 = xb[c4];
                a0 += wv.x * v0.x + wv.y * v0.y + wv.z * v0.z + wv.w * v0.w;
                a1 += wv.x * v1.x + wv.y * v1.y + wv.z * v1.z + wv.w * v1.w;
            }
            #pragma unroll
            for (int e = 0; e < 2; ++e) {
                float acc = e ? a1 : a0;
                float t = (acc - mn) * scale + bt;
                float s = t / (1.f + expf(-t));      // SiLU
                float sq = s * s;                     // squash over 8-lane group
                sq += __shfl_xor(sq, 1);
                sq += __shfl_xor(sq, 2);
                sq += __shfl_xor(sq, 4);
                float f = (sq / (1.f + sq)) * rsqrtf(sq + 1e-7f);
                child_t[(size_t)(m0 + e) * 64 + o] = s * f;
            }
        }
        return;
    }

    // ================= kB role =================
    {
        const float4* wt24 = reinterpret_cast<const float4*>(wt2);
        float4* wl4w = reinterpret_cast<float4*>(wl);
        #pragma unroll
        for (int k = 0; k < 16; ++k)
            wl4w[k * 256 + threadIdx.x] = wt24[k * 256 + threadIdx.x];
    }
    __syncthreads();

    int m0 = ((blockIdx.x - 512) * 4 + wid) * 4;  // 4 consecutive px, same row
    int b = m0 >> 10, hw0 = m0 & 1023;
    int yy = hw0 >> 5, xx0 = hw0 & 31;
    const float* xb = xt + (size_t)b * HW * 256;

    float acc[4][8];
    #pragma unroll
    for (int px = 0; px < 4; ++px)
        #pragma unroll
        for (int oc = 0; oc < 8; ++oc) acc[px][oc] = 0.f;

    #pragma unroll
    for (int tap = 0; tap < 9; ++tap) {
        int ky = tap / 3 - 1, kx = tap % 3 - 1;
        int yq = yy + ky;
        bool vy = (yq >= 0) && (yq <= Hd - 1);
        float4 xv[4];
        #pragma unroll
        for (int px = 0; px < 4; ++px) {
            int xq = xx0 + px + kx;
            bool ok = vy && (xq >= 0) && (xq <= Wd - 1);
            float4 z; z.x = z.y = z.z = z.w = 0.f;
            xv[px] = ok ? *reinterpret_cast<const float4*>(
                              xb + (size_t)(yq * Wd + xq) * 256 + lane * 4)
                        : z;
        }
        #pragma unroll
        for (int oc = 0; oc < 8; ++oc) {
            float4 wv = (tap < 8)
                ? *reinterpret_cast<const float4*>(wl + (tap * 8 + oc) * 256 + lane * 4)
                : *reinterpret_cast<const float4*>(wt2 + (8 * 8 + oc) * 256 + lane * 4);
            #pragma unroll
            for (int px = 0; px < 4; ++px)
                acc[px][oc] += xv[px].x * wv.x + xv[px].y * wv.y +
                               xv[px].z * wv.z + xv[px].w * wv.w;
        }
    }

    // reduce-scatter to lane target (px = lane&3, oc = (lane>>2)&7)
    int l0 = lane & 1, l1 = (lane >> 1) & 1;
    int o2 = (lane >> 2) & 1, o3 = (lane >> 3) & 1, o4 = (lane >> 4) & 1;
    float y1[2][8];
    #pragma unroll
    for (int ph = 0; ph < 2; ++ph)
        #pragma unroll
        for (int oc = 0; oc < 8; ++oc) {
            float keep = l0 ? acc[(ph << 1) | 1][oc] : acc[(ph << 1) | 0][oc];
            float send = l0 ? acc[(ph << 1) | 0][oc] : acc[(ph << 1) | 1][oc];
            y1[ph][oc] = keep + dppx<0xB1>(send);
        }
    float y2[8];
    #pragma unroll
    for (int oc = 0; oc < 8; ++oc) {
        float keep = l1 ? y1[1][oc] : y1[0][oc];
        float send = l1 ? y1[0][oc] : y1[1][oc];
        y2[oc] = keep + dppx<0x4E>(send);
    }
    float z4[4];
    #pragma unroll
    for (int oh = 0; oh < 4; ++oh) {
        float keep = o2 ? y2[(oh << 1) | 1] : y2[(oh << 1) | 0];
        float send = o2 ? y2[(oh << 1) | 0] : y2[(oh << 1) | 1];
        z4[oh] = keep + __shfl_xor(send, 4);
    }
    float w2[2];
    #pragma unroll
    for (int oh = 0; oh < 2; ++oh) {
        float keep = o3 ? z4[(oh << 1) | 1] : z4[(oh << 1) | 0];
        float send = o3 ? z4[(oh << 1) | 0] : z4[(oh << 1) | 1];
        w2[oh] = keep + dppx<0x128>(send);
    }
    {
        float keep = o4 ? w2[1] : w2[0];
        float send = o4 ? w2[0] : w2[1];
        float s = keep + __shfl_xor(send, 16);
        s += __shfl_xor(s, 32);
        if (lane < 32) {
            int px = lane & 3, oc = (lane >> 2) & 7;
            float t = tanhf(s + ob[oc]);
            int coord = oc & 1, si = oc >> 1;
            int xx = xx0 + px;
            float base = coord ? (-1.f + yy * (2.f / 31.f))
                               : (-1.f + xx * (2.f / 31.f));
            grids[(size_t)(m0 + px) * 8 + si * 2 + coord] =
                base + t * (1.f / 15.5f);
        }
    }
}

// ---------------- Kernel D v14: LDS weights + DPP routing -------------------
// 2048 blocks x 256 thr (4 waves), 1 pixel/wave, launch_bounds(256,2)
// (the only non-spilling point: ~84 VGPR need vs 256/N cap — R7/R12/R16).
// 64 KB fp16 weight table staged in LDS (linear copy, zero index changes);
// u_hat reads become ds_read_b128 (~12cyc) instead of L2 (~200cyc) — the
// DS pipe is idle now that routing runs on DPP/VALU.
__global__ __launch_bounds__(256, 2) void kD(const float* __restrict__ child_t,
        const float* __restrict__ grids, const _Float16* __restrict__ wth,
        float* __restrict__ out) {
    __shared__ float wl[16384];               // 64 KB weight table
    __shared__ float vband_s[4][128];         // per-wave v broadcast, 2 KB
    {
        const float4* src = reinterpret_cast<const float4*>(wth);
        float4* dst = reinterpret_cast<float4*>(wl);
        #pragma unroll
        for (int k = 0; k < 16; ++k)
            dst[k * 256 + threadIdx.x] = src[k * 256 + threadIdx.x];
    }
    __syncthreads();

    int wid = threadIdx.x >> 6, lane = threadIdx.x & 63;
    float* vband = vband_s[wid];
    int m = blockIdx.x * 4 + wid;             // pixel
    int b = m >> 10, hw = m & 1023;
    int n = (lane & 3) | ((lane >> 1) & 0x1C);
    int half = (lane >> 2) & 1;
    int si = n >> 3, ch = n & 7;
    // d-slot owned after reduce-scatter (bit-reversed n bits 0..3)
    int dsl = (n & 1) * 8 + ((n >> 1) & 1) * 4 + ((n >> 2) & 1) * 2 + ((n >> 3) & 1);

    // ---- bilinear sampling (align_corners=True, zeros padding), f32 ----
    float gx = grids[m * 8 + si * 2 + 0];
    float gy = grids[m * 8 + si * 2 + 1];
    float xf = (gx + 1.f) * 0.5f * 31.f;
    float yf = (gy + 1.f) * 0.5f * 31.f;
    float x0 = floorf(xf), y0 = floorf(yf);
    float wx1 = xf - x0, wx0 = 1.f - wx1;
    float wy1 = yf - y0, wy0 = 1.f - wy1;
    float sf[8] = {0.f, 0.f, 0.f, 0.f, 0.f, 0.f, 0.f, 0.f};
    const float* cb = child_t + (size_t)b * HW * 64 + ch * 8;
    #pragma unroll
    for (int cy = 0; cy < 2; ++cy) {
        float yq = y0 + (float)cy;
        bool vy = (yq >= 0.f) && (yq <= 31.f);
        float wy = cy ? wy1 : wy0;
        #pragma unroll
        for (int cx = 0; cx < 2; ++cx) {
            float xq = x0 + (float)cx;
            bool ok = vy && (xq >= 0.f) && (xq <= 31.f);
            if (!ok) continue;
            float w = wy * (cx ? wx1 : wx0);
            const float* cp = cb + (size_t)((int)yq * Wd + (int)xq) * 64;
            float4 v0 = *reinterpret_cast<const float4*>(cp);
            float4 v1 = *reinterpret_cast<const float4*>(cp + 4);
            sf[0] += w * v0.x; sf[1] += w * v0.y;
            sf[2] += w * v0.z; sf[3] += w * v0.w;
            sf[4] += w * v1.x; sf[5] += w * v1.y;
            sf[6] += w * v1.z; sf[7] += w * v1.w;
        }
    }
    half2_t sh0 = {(_Float16)sf[0], (_Float16)sf[1]};
    half2_t sh1 = {(_Float16)sf[2], (_Float16)sf[3]};
    half2_t sh2 = {(_Float16)sf[4], (_Float16)sf[5]};
    half2_t sh3 = {(_Float16)sf[6], (_Float16)sf[7]};

    // ---- u_hat = W[n] . samp : fp16 from LDS, ds_read_b128 ----
    float u[4][16];
    const float4* wt4 = reinterpret_cast<const float4*>(wl);
    #pragma unroll
    for (int o = 0; o < 4; ++o) {
        #pragma unroll
        for (int d = 0; d < 16; ++d) {
            float4 wv = wt4[(o * 16 + d) * 64 + lane];
            F2H a0, a1, a2, a3;
            a0.f = wv.x; a1.f = wv.y; a2.f = wv.z; a3.f = wv.w;
            float acc = dot2(a0.h, sh0, 0.f);
            acc = dot2(a1.h, sh1, acc);
            acc = dot2(a2.h, sh2, acc);
            acc = dot2(a3.h, sh3, acc);
            u[o][d] = acc;
        }
    }

    // ---- dynamic routing (3 iters); iter 0 has exact c = 1/8 ----
    float bl[4] = {0.f, 0.f, 0.f, 0.f};
    #pragma unroll
    for (int it = 0; it < 3; ++it) {
        float ex[4], rs;
        if (it == 0) {
            ex[0] = ex[1] = ex[2] = ex[3] = 1.f;
            rs = 0.125f;                      // softmax(0) = 1/8 exactly
        } else {
            float mx = fmaxf(fmaxf(bl[0], bl[1]), fmaxf(bl[2], bl[3]));
            mx = fmaxf(mx, __shfl_xor(mx, 4));     // half partner = xor4
            float ssum = 0.f;
            #pragma unroll
            for (int k = 0; k < 4; ++k) { ex[k] = expf(bl[k] - mx); ssum += ex[k]; }
            ssum += __shfl_xor(ssum, 4);
            rs = 1.f / ssum;
        }

        float sval[4];
        #pragma unroll
        for (int o = 0; o < 4; ++o) {
            float cc = ex[o] * rs;
            // reduce-scatter over n: xor1(DPP), xor2(DPP), xor8(DPP),
            // xor16(DS), xor32(DS)
            float y[8];
            #pragma unroll
            for (int d = 0; d < 8; ++d) {
                float t = (n & 1) ? cc * u[o][d] : cc * u[o][d + 8]; // send
                float k = (n & 1) ? cc * u[o][d + 8] : cc * u[o][d]; // keep
                y[d] = k + dppx<0xB1>(t);
            }
            float z[4];
            #pragma unroll
            for (int d = 0; d < 4; ++d) {
                float t = (n & 2) ? y[d] : y[d + 4];
                float k = (n & 2) ? y[d + 4] : y[d];
                z[d] = k + dppx<0x4E>(t);
            }
            float w2[2];
            #pragma unroll
            for (int d = 0; d < 2; ++d) {
                float t = (n & 4) ? z[d] : z[d + 2];
                float k = (n & 4) ? z[d + 2] : z[d];
                w2[d] = k + dppx<0x128>(t);
            }
            float t4 = (n & 8) ? w2[0] : w2[1];
            float k4 = (n & 8) ? w2[1] : w2[0];
            float s1 = k4 + __shfl_xor(t4, 16);
            s1 += __shfl_xor(s1, 32);                 // merge n-bit4 halves
            sval[o] = s1;
        }
        // squash: sq_o = sum over 16 d-owners (lane bits {0,1,3,4})
        #pragma unroll
        for (int o = 0; o < 4; ++o) {
            float q = sval[o] * sval[o];
            q += dppx<0xB1>(q);
            q += dppx<0x4E>(q);
            q += dppx<0x128>(q);
            q += __shfl_xor(q, 16);
            float f = (q / (1.f + q)) / sqrtf(q + 1e-7f);
            if ((lane & 32) == 0)                     // one writer per (o,d)
                vband[(half * 4 + o) * 16 + dsl] = sval[o] * f;
        }
        if (it < 2) {
            // agreement: b[n][o] += sum_d u[n][o][d] * v[o][d]
            #pragma unroll
            for (int o = 0; o < 4; ++o) {
                const float4* vr = reinterpret_cast<const float4*>(
                    vband + (half * 4 + o) * 16);
                float4 v0 = vr[0], v1 = vr[1], v2 = vr[2], v3 = vr[3];
                float agg = u[o][0] * v0.x + u[o][1] * v0.y +
                            u[o][2] * v0.z + u[o][3] * v0.w +
                            u[o][4] * v1.x + u[o][5] * v1.y +
                            u[o][6] * v1.z + u[o][7] * v1.w +
                            u[o][8] * v2.x + u[o][9] * v2.y +
                            u[o][10] * v2.z + u[o][11] * v2.w +
                            u[o][12] * v3.x + u[o][13] * v3.y +
                            u[o][14] * v3.z + u[o][15] * v3.w;
                bl[o] += agg;
            }
        } else {
            // output: each lane writes 2 dwords of out[b][och][d][hw]
            int o_own = lane >> 4;                    // bits 4,5
            int och = half * 4 + o_own;
            int d0 = ((lane & 3) | ((lane >> 1) & 4)) * 2;  // bits {0,1,3}
            float va = vband[och * 16 + d0 + 0];
            float vb = vband[och * 16 + d0 + 1];
            float* op = out + ((size_t)b * 128 + och * 16) * HW + hw;
            op[(size_t)(d0 + 0) * HW] = va;
            op[(size_t)(d0 + 1) * HW] = vb;
        }
    }
}

extern "C" void kernel_launch(void* const* d_in, const int* in_sizes, int n_in,
                              void* d_out, int out_size, void* d_ws, size_t ws_size,
                              hipStream_t stream) {
    const float* x     = (const float*)d_in[0];
    const float* pw    = (const float*)d_in[1];
    const float* gamma = (const float*)d_in[2];
    const float* beta  = (const float*)d_in[3];
    const float* mean  = (const float*)d_in[4];
    const float* var   = (const float*)d_in[5];
    const float* ow    = (const float*)d_in[6];
    const float* ob    = (const float*)d_in[7];
    const float* rw    = (const float*)d_in[8];
    float* out = (float*)d_out;
    char* ws = (char*)d_ws;
    float*     child_t = (float*)ws;                 // 2 MiB
    float*     grids   = (float*)(ws + 2097152);     // 256 KiB
    _Float16*  wth     = (_Float16*)(ws + 2359296);  // 64 KiB
    float*     wt2     = (float*)(ws + 2424832);     // 72 KiB
    float*     xt      = (float*)(ws + 2498560);     // 8 MiB

    hipLaunchKernelGGL(kTP, dim3(712), dim3(256), 0, stream,
                       x, ow, rw, xt, wt2, wth);
    hipLaunchKernelGGL(kAB, dim3(1024), dim3(256), 0, stream,
                       xt, pw, gamma, beta, mean, var, wt2, ob,
                       child_t, grids);
    hipLaunchKernelGGL(kD, dim3(2048), dim3(256), 0, stream,
                       child_t, grids, wth, out);
}

// Round 18
// 76.190 us; speedup vs baseline: 1.5090x; 1.1962x over previous
//
#include <hip/hip_runtime.h>
#include <math.h>

#define HW 1024
#define Hd 32
#define Wd 32
#define Bn 8
#define Cc 256

typedef _Float16 half2_t __attribute__((ext_vector_type(2)));
union F2H { float f; half2_t h; };

static __device__ __forceinline__ float dot2(half2_t a, half2_t b, float c) {
#if __has_builtin(__builtin_amdgcn_fdot2)
    return __builtin_amdgcn_fdot2(a, b, c, false);
#else
    return c + (float)a.x * (float)b.x + (float)a.y * (float)b.y;
#endif
}

// DPP lane-xor on the VALU pipe (no DS). CTRL: 0xB1=xor1, 0x4E=xor2,
// 0x128=row_ror:8=xor8 (within 16-lane rows).
template<int CTRL>
static __device__ __forceinline__ float dppx(float v) {
    union { float f; int i; } a, r;
    a.f = v;
    r.i = __builtin_amdgcn_update_dpp(0, a.i, CTRL, 0xF, 0xF, true);
    return r.f;
}

// ---------------- Kernel TPA: transpose + weight prep + primary caps --------
// bid <512      : transpose x[b][c][hw] -> xt[pix][c]   (for kB only now)
// 512..583      : conv-w transpose to wt2[tap][oc][c]
// 584..711      : routing-W fp16 pack wth (kD v7 lane map)
// 712..1223     : kA-role — per-block x slice staged+transposed in LDS,
//                 1x1 conv + BN + SiLU + squash (arithmetic identical to R10)
__global__ __launch_bounds__(256) void kTPA(const float* __restrict__ x,
        const float* __restrict__ ow, const float* __restrict__ rw,
        const float* __restrict__ pw, const float* __restrict__ gamma,
        const float* __restrict__ beta, const float* __restrict__ mean,
        const float* __restrict__ var,
        float* __restrict__ xt, float* __restrict__ wt2,
        _Float16* __restrict__ wth, float* __restrict__ child_t) {
    __shared__ float lds[20480];              // 80 KB carved per role
    int bid = blockIdx.x;
    int tid = threadIdx.x;
    if (bid < 512) {
        float (*tile)[65] = (float(*)[65])lds;
        int b = bid >> 6, ct = (bid >> 4) & 3, ht = bid & 15;
        int c0 = ct * 64, hw0 = ht * 64;
        int tr = tid >> 6, tc = tid & 63;
        const float* xb = x + ((size_t)b * 256 + c0) * 1024 + hw0;
        #pragma unroll
        for (int k = 0; k < 16; ++k) {
            int c = tr + k * 4;
            tile[c][tc] = xb[(size_t)c * 1024 + tc];
        }
        __syncthreads();
        float* xo = xt + ((size_t)b * 1024 + hw0) * 256 + c0;
        #pragma unroll
        for (int k = 0; k < 16; ++k) {
            int hwl = tr + k * 4;
            xo[(size_t)hwl * 256 + tc] = tile[tc][hwl];
        }
    } else if (bid < 584) {
        int t = (bid - 512) * 256 + tid;      // 18432
        int c = t & 255, oc = (t >> 8) & 7, tap = t >> 11;
        wt2[t] = ow[(oc * 256 + c) * 9 + tap];
    } else if (bid < 712) {
        int t = (bid - 584) * 256 + tid;      // 32768
        int i = t & 7, l = (t >> 3) & 63, j = t >> 9;
        int n = (l & 3) | ((l >> 1) & 0x1C);  // kD v7 lane map
        int half = (l >> 2) & 1;
        int o = j >> 4, d = j & 15;
        wth[t] = (_Float16)rw[n * 1024 + half * 512 + o * 128 + d * 8 + i];
    } else {
        // ================= kA role (reads x directly) =================
        float* xs = lds;                      // 16 px x 256 c = 16 KB
        float* wl = lds + 4096;               // 64 KB swizzled weights
        {
            const float4* pw4 = reinterpret_cast<const float4*>(pw);
            #pragma unroll
            for (int k = 0; k < 16; ++k) {
                int f = k * 256 + tid;
                float4 v = pw4[f];
                int o = f >> 6, c4 = f & 63;
                *reinterpret_cast<float4*>(
                    wl + c4 * 256 + (((o ^ c4) & 63) << 2)) = v;
            }
        }
        int m0b = (bid - 712) * 16;           // 16 consecutive px, same batch
        int b = m0b >> 10, hw0 = m0b & 1023;
        {
            int c = tid;
            const float4* xr = reinterpret_cast<const float4*>(
                x + ((size_t)b * 256 + c) * 1024 + hw0);
            float4 q0 = xr[0], q1 = xr[1], q2 = xr[2], q3 = xr[3];
            xs[0 * 256 + c] = q0.x;  xs[1 * 256 + c] = q0.y;
            xs[2 * 256 + c] = q0.z;  xs[3 * 256 + c] = q0.w;
            xs[4 * 256 + c] = q1.x;  xs[5 * 256 + c] = q1.y;
            xs[6 * 256 + c] = q1.z;  xs[7 * 256 + c] = q1.w;
            xs[8 * 256 + c] = q2.x;  xs[9 * 256 + c] = q2.y;
            xs[10 * 256 + c] = q2.z; xs[11 * 256 + c] = q2.w;
            xs[12 * 256 + c] = q3.x; xs[13 * 256 + c] = q3.y;
            xs[14 * 256 + c] = q3.z; xs[15 * 256 + c] = q3.w;
        }
        __syncthreads();
        int wid = tid >> 6, lane = tid & 63;
        int o = lane;
        float scale = gamma[o] * rsqrtf(var[o] + 1e-5f);
        float mn = mean[o], bt = beta[o];
        const float4* wl4 = reinterpret_cast<const float4*>(wl);
        #pragma unroll
        for (int pp = 0; pp < 4; pp += 2) {   // 2 px share each weight pass
            int lp = wid * 4 + pp;
            const float4* xa = reinterpret_cast<const float4*>(xs + lp * 256);
            const float4* xb = reinterpret_cast<const float4*>(xs + (lp + 1) * 256);
            float a0 = 0.f, a1 = 0.f;
            #pragma unroll 8
            for (int c4 = 0; c4 < 64; ++c4) {
                float4 wv = wl4[c4 * 64 + (lane ^ (c4 & 63))];
                float4 v0 = xa[c4], v1 = xb[c4];
                a0 += wv.x * v0.x + wv.y * v0.y + wv.z * v0.z + wv.w * v0.w;
                a1 += wv.x * v1.x + wv.y * v1.y + wv.z * v1.z + wv.w * v1.w;
            }
            #pragma unroll
            for (int e = 0; e < 2; ++e) {
                float acc = e ? a1 : a0;
                float t = (acc - mn) * scale + bt;
                float s = t / (1.f + expf(-t));      // SiLU
                float sq = s * s;                     // squash over 8-lane group
                sq += __shfl_xor(sq, 1);
                sq += __shfl_xor(sq, 2);
                sq += __shfl_xor(sq, 4);
                float f = (sq / (1.f + sq)) * rsqrtf(sq + 1e-7f);
                child_t[(size_t)(m0b + lp + e) * 64 + o] = s * f;
            }
        }
    }
}

// ---------------- Kernel B: 3x3 offset conv + tanh -> grids (reads xt) ------
__global__ __launch_bounds__(256) void kB(const float* __restrict__ xt,
        const float* __restrict__ wt2, const float* __restrict__ ob,
        float* __restrict__ grids) {
    __shared__ float wl[16384];               // 64 KB
    int wid = threadIdx.x >> 6, lane = threadIdx.x & 63;
    {
        const float4* wt24 = reinterpret_cast<const float4*>(wt2);
        float4* wl4w = reinterpret_cast<float4*>(wl);
        #pragma unroll
        for (int k = 0; k < 16; ++k)
            wl4w[k * 256 + threadIdx.x] = wt24[k * 256 + threadIdx.x];
    }
    __syncthreads();

    int m0 = (blockIdx.x * 4 + wid) * 4;      // 4 consecutive px, same row
    int b = m0 >> 10, hw0 = m0 & 1023;
    int yy = hw0 >> 5, xx0 = hw0 & 31;
    const float* xb = xt + (size_t)b * HW * 256;

    float acc[4][8];
    #pragma unroll
    for (int px = 0; px < 4; ++px)
        #pragma unroll
        for (int oc = 0; oc < 8; ++oc) acc[px][oc] = 0.f;

    #pragma unroll
    for (int tap = 0; tap < 9; ++tap) {
        int ky = tap / 3 - 1, kx = tap % 3 - 1;
        int yq = yy + ky;
        bool vy = (yq >= 0) && (yq <= Hd - 1);
        float4 xv[4];
        #pragma unroll
        for (int px = 0; px < 4; ++px) {
            int xq = xx0 + px + kx;
            bool ok = vy && (xq >= 0) && (xq <= Wd - 1);
            float4 z; z.x = z.y = z.z = z.w = 0.f;
            xv[px] = ok ? *reinterpret_cast<const float4*>(
                              xb + (size_t)(yq * Wd + xq) * 256 + lane * 4)
                        : z;
        }
        #pragma unroll
        for (int oc = 0; oc < 8; ++oc) {
            float4 wv = (tap < 8)
                ? *reinterpret_cast<const float4*>(wl + (tap * 8 + oc) * 256 + lane * 4)
                : *reinterpret_cast<const float4*>(wt2 + (8 * 8 + oc) * 256 + lane * 4);
            #pragma unroll
            for (int px = 0; px < 4; ++px)
                acc[px][oc] += xv[px].x * wv.x + xv[px].y * wv.y +
                               xv[px].z * wv.z + xv[px].w * wv.w;
        }
    }

    // reduce-scatter to lane target (px = lane&3, oc = (lane>>2)&7)
    int l0 = lane & 1, l1 = (lane >> 1) & 1;
    int o2 = (lane >> 2) & 1, o3 = (lane >> 3) & 1, o4 = (lane >> 4) & 1;
    float y1[2][8];
    #pragma unroll
    for (int ph = 0; ph < 2; ++ph)
        #pragma unroll
        for (int oc = 0; oc < 8; ++oc) {
            float keep = l0 ? acc[(ph << 1) | 1][oc] : acc[(ph << 1) | 0][oc];
            float send = l0 ? acc[(ph << 1) | 0][oc] : acc[(ph << 1) | 1][oc];
            y1[ph][oc] = keep + dppx<0xB1>(send);
        }
    float y2[8];
    #pragma unroll
    for (int oc = 0; oc < 8; ++oc) {
        float keep = l1 ? y1[1][oc] : y1[0][oc];
        float send = l1 ? y1[0][oc] : y1[1][oc];
        y2[oc] = keep + dppx<0x4E>(send);
    }
    float z4[4];
    #pragma unroll
    for (int oh = 0; oh < 4; ++oh) {
        float keep = o2 ? y2[(oh << 1) | 1] : y2[(oh << 1) | 0];
        float send = o2 ? y2[(oh << 1) | 0] : y2[(oh << 1) | 1];
        z4[oh] = keep + __shfl_xor(send, 4);
    }
    float w2[2];
    #pragma unroll
    for (int oh = 0; oh < 2; ++oh) {
        float keep = o3 ? z4[(oh << 1) | 1] : z4[(oh << 1) | 0];
        float send = o3 ? z4[(oh << 1) | 0] : z4[(oh << 1) | 1];
        w2[oh] = keep + dppx<0x128>(send);
    }
    {
        float keep = o4 ? w2[1] : w2[0];
        float send = o4 ? w2[0] : w2[1];
        float s = keep + __shfl_xor(send, 16);
        s += __shfl_xor(s, 32);
        if (lane < 32) {
            int px = lane & 3, oc = (lane >> 2) & 7;
            float t = tanhf(s + ob[oc]);
            int coord = oc & 1, si = oc >> 1;
            int xx = xx0 + px;
            float base = coord ? (-1.f + yy * (2.f / 31.f))
                               : (-1.f + xx * (2.f / 31.f));
            grids[(size_t)(m0 + px) * 8 + si * 2 + coord] =
                base + t * (1.f / 15.5f);
        }
    }
}

// ---------------- Kernel D v7 (R10 best, byte-identical): -------------------
// 2048 blocks x 256 thr (4 waves), 1 pixel/wave. fp16 weights from L2.
// lane map: half = lane bit2, n = lane bits {0,1,3,4,5}; butterfly masks
// xor{1,2,8} are DPP (VALU); only xor{16,32} touch DS.
__global__ __launch_bounds__(256, 2) void kD(const float* __restrict__ child_t,
        const float* __restrict__ grids, const _Float16* __restrict__ wth,
        float* __restrict__ out) {
    __shared__ float vband_s[4][128];         // per-wave v broadcast, 2 KB
    int wid = threadIdx.x >> 6, lane = threadIdx.x & 63;
    float* vband = vband_s[wid];
    int m = blockIdx.x * 4 + wid;             // pixel
    int b = m >> 10, hw = m & 1023;
    int n = (lane & 3) | ((lane >> 1) & 0x1C);
    int half = (lane >> 2) & 1;
    int si = n >> 3, ch = n & 7;
    // d-slot owned after reduce-scatter (bit-reversed n bits 0..3)
    int dsl = (n & 1) * 8 + ((n >> 1) & 1) * 4 + ((n >> 2) & 1) * 2 + ((n >> 3) & 1);

    // ---- bilinear sampling (align_corners=True, zeros padding), f32 ----
    float gx = grids[m * 8 + si * 2 + 0];
    float gy = grids[m * 8 + si * 2 + 1];
    float xf = (gx + 1.f) * 0.5f * 31.f;
    float yf = (gy + 1.f) * 0.5f * 31.f;
    float x0 = floorf(xf), y0 = floorf(yf);
    float wx1 = xf - x0, wx0 = 1.f - wx1;
    float wy1 = yf - y0, wy0 = 1.f - wy1;
    float sf[8] = {0.f, 0.f, 0.f, 0.f, 0.f, 0.f, 0.f, 0.f};
    const float* cb = child_t + (size_t)b * HW * 64 + ch * 8;
    #pragma unroll
    for (int cy = 0; cy < 2; ++cy) {
        float yq = y0 + (float)cy;
        bool vy = (yq >= 0.f) && (yq <= 31.f);
        float wy = cy ? wy1 : wy0;
        #pragma unroll
        for (int cx = 0; cx < 2; ++cx) {
            float xq = x0 + (float)cx;
            bool ok = vy && (xq >= 0.f) && (xq <= 31.f);
            if (!ok) continue;
            float w = wy * (cx ? wx1 : wx0);
            const float* cp = cb + (size_t)((int)yq * Wd + (int)xq) * 64;
            float4 v0 = *reinterpret_cast<const float4*>(cp);
            float4 v1 = *reinterpret_cast<const float4*>(cp + 4);
            sf[0] += w * v0.x; sf[1] += w * v0.y;
            sf[2] += w * v0.z; sf[3] += w * v0.w;
            sf[4] += w * v1.x; sf[5] += w * v1.y;
            sf[6] += w * v1.z; sf[7] += w * v1.w;
        }
    }
    half2_t sh0 = {(_Float16)sf[0], (_Float16)sf[1]};
    half2_t sh1 = {(_Float16)sf[2], (_Float16)sf[3]};
    half2_t sh2 = {(_Float16)sf[4], (_Float16)sf[5]};
    half2_t sh3 = {(_Float16)sf[6], (_Float16)sf[7]};

    // ---- u_hat = W[n] . samp : fp16 from global/L2, coalesced b128 ----
    float u[4][16];
    const float4* wt4 = reinterpret_cast<const float4*>(wth);
    #pragma unroll
    for (int o = 0; o < 4; ++o) {
        #pragma unroll
        for (int d = 0; d < 16; ++d) {
            float4 wv = wt4[(o * 16 + d) * 64 + lane];
            F2H a0, a1, a2, a3;
            a0.f = wv.x; a1.f = wv.y; a2.f = wv.z; a3.f = wv.w;
            float acc = dot2(a0.h, sh0, 0.f);
            acc = dot2(a1.h, sh1, acc);
            acc = dot2(a2.h, sh2, acc);
            acc = dot2(a3.h, sh3, acc);
            u[o][d] = acc;
        }
    }

    // ---- dynamic routing (3 iters); iter 0 has exact c = 1/8 ----
    float bl[4] = {0.f, 0.f, 0.f, 0.f};
    #pragma unroll
    for (int it = 0; it < 3; ++it) {
        float ex[4], rs;
        if (it == 0) {
            ex[0] = ex[1] = ex[2] = ex[3] = 1.f;
            rs = 0.125f;                      // softmax(0) = 1/8 exactly
        } else {
            float mx = fmaxf(fmaxf(bl[0], bl[1]), fmaxf(bl[2], bl[3]));
            mx = fmaxf(mx, __shfl_xor(mx, 4));     // half partner = xor4
            float ssum = 0.f;
            #pragma unroll
            for (int k = 0; k < 4; ++k) { ex[k] = expf(bl[k] - mx); ssum += ex[k]; }
            ssum += __shfl_xor(ssum, 4);
            rs = 1.f / ssum;
        }

        float sval[4];
        #pragma unroll
        for (int o = 0; o < 4; ++o) {
            float cc = ex[o] * rs;
            // reduce-scatter over n: xor1(DPP), xor2(DPP), xor8(DPP),
            // xor16(DS), xor32(DS)
            float y[8];
            #pragma unroll
            for (int d = 0; d < 8; ++d) {
                float t = (n & 1) ? cc * u[o][d] : cc * u[o][d + 8]; // send
                float k = (n & 1) ? cc * u[o][d + 8] : cc * u[o][d]; // keep
                y[d] = k + dppx<0xB1>(t);
            }
            float z[4];
            #pragma unroll
            for (int d = 0; d < 4; ++d) {
                float t = (n & 2) ? y[d] : y[d + 4];
                float k = (n & 2) ? y[d + 4] : y[d];
                z[d] = k + dppx<0x4E>(t);
            }
            float w2[2];
            #pragma unroll
            for (int d = 0; d < 2; ++d) {
                float t = (n & 4) ? z[d] : z[d + 2];
                float k = (n & 4) ? z[d + 2] : z[d];
                w2[d] = k + dppx<0x128>(t);
            }
            float t4 = (n & 8) ? w2[0] : w2[1];
            float k4 = (n & 8) ? w2[1] : w2[0];
            float s1 = k4 + __shfl_xor(t4, 16);
            s1 += __shfl_xor(s1, 32);                 // merge n-bit4 halves
            sval[o] = s1;
        }
        // squash: sq_o = sum over 16 d-owners (lane bits {0,1,3,4})
        #pragma unroll
        for (int o = 0; o < 4; ++o) {
            float q = sval[o] * sval[o];
            q += dppx<0xB1>(q);
            q += dppx<0x4E>(q);
            q += dppx<0x128>(q);
            q += __shfl_xor(q, 16);
            float f = (q / (1.f + q)) / sqrtf(q + 1e-7f);
            if ((lane & 32) == 0)                     // one writer per (o,d)
                vband[(half * 4 + o) * 16 + dsl] = sval[o] * f;
        }
        if (it < 2) {
            // agreement: b[n][o] += sum_d u[n][o][d] * v[o][d]
            #pragma unroll
            for (int o = 0; o < 4; ++o) {
                const float4* vr = reinterpret_cast<const float4*>(
                    vband + (half * 4 + o) * 16);
                float4 v0 = vr[0], v1 = vr[1], v2 = vr[2], v3 = vr[3];
                float agg = u[o][0] * v0.x + u[o][1] * v0.y +
                            u[o][2] * v0.z + u[o][3] * v0.w +
                            u[o][4] * v1.x + u[o][5] * v1.y +
                            u[o][6] * v1.z + u[o][7] * v1.w +
                            u[o][8] * v2.x + u[o][9] * v2.y +
                            u[o][10] * v2.z + u[o][11] * v2.w +
                            u[o][12] * v3.x + u[o][13] * v3.y +
                            u[o][14] * v3.z + u[o][15] * v3.w;
                bl[o] += agg;
            }
        } else {
            // output: each lane writes 2 dwords of out[b][och][d][hw]
            int o_own = lane >> 4;                    // bits 4,5
            int och = half * 4 + o_own;
            int d0 = ((lane & 3) | ((lane >> 1) & 4)) * 2;  // bits {0,1,3}
            float va = vband[och * 16 + d0 + 0];
            float vb = vband[och * 16 + d0 + 1];
            float* op = out + ((size_t)b * 128 + och * 16) * HW + hw;
            op[(size_t)(d0 + 0) * HW] = va;
            op[(size_t)(d0 + 1) * HW] = vb;
        }
    }
}

extern "C" void kernel_launch(void* const* d_in, const int* in_sizes, int n_in,
                              void* d_out, int out_size, void* d_ws, size_t ws_size,
                              hipStream_t stream) {
    const float* x     = (const float*)d_in[0];
    const float* pw    = (const float*)d_in[1];
    const float* gamma = (const float*)d_in[2];
    const float* beta  = (const float*)d_in[3];
    const float* mean  = (const float*)d_in[4];
    const float* var   = (const float*)d_in[5];
    const float* ow    = (const float*)d_in[6];
    const float* ob    = (const float*)d_in[7];
    const float* rw    = (const float*)d_in[8];
    float* out = (float*)d_out;
    char* ws = (char*)d_ws;
    float*     child_t = (float*)ws;                 // 2 MiB
    float*     grids   = (float*)(ws + 2097152);     // 256 KiB
    _Float16*  wth     = (_Float16*)(ws + 2359296);  // 64 KiB
    float*     wt2     = (float*)(ws + 2424832);     // 72 KiB
    float*     xt      = (float*)(ws + 2498560);     // 8 MiB

    hipLaunchKernelGGL(kTPA, dim3(1224), dim3(256), 0, stream,
                       x, ow, rw, pw, gamma, beta, mean, var,
                       xt, wt2, wth, child_t);
    hipLaunchKernelGGL(kB, dim3(512), dim3(256), 0, stream,
                       xt, wt2, ob, grids);
    hipLaunchKernelGGL(kD, dim3(2048), dim3(256), 0, stream,
                       child_t, grids, wth, out);
}